// Round 1
// baseline (123.744 us; speedup 1.0000x reference)
//
#include <hip/hip_runtime.h>

#define BATCH 8
#define SEQ 8192
#define DIM 1024

// Detect whether boundaries buffer is 1-byte bool or int32 (0/1) storage.
// If int32 little-endian with values 0/1, all bytes at (i % 4 != 0) are zero.
// If u8 random 0/1, nonzero bytes at those offsets appear immediately.
// Only scans BATCH*SEQ bytes = 64 KB, which is within the buffer under
// either interpretation.
__global__ void detect_u8_kernel(const unsigned char* __restrict__ p, int n_bytes,
                                 int* __restrict__ flag) {
    int any = 0;
    for (int i = blockIdx.x * blockDim.x + threadIdx.x; i < n_bytes;
         i += blockDim.x * gridDim.x) {
        if ((i & 3) != 0 && p[i] != 0) any = 1;
    }
    if (__any(any)) {
        if ((threadIdx.x & 63) == 0) atomicOr(flag, 1);
    }
}

// One wave per batch: sequential 64-wide scan over SEQ positions.
// Pass 1: total boundary count (num_tokens). Pass 2: stable-partition dest
// index for every position; record source row for dests < MC.
__global__ void scan_kernel(const void* __restrict__ bnd, const int* __restrict__ flag,
                            int* __restrict__ ntok, int* __restrict__ srcmap,
                            float* __restrict__ ntok_out, int MC) {
    const int b = blockIdx.x;
    const int lane = threadIdx.x;  // 64 threads = 1 wave
    const bool u8 = (*flag != 0);
    const unsigned char* p8 = (const unsigned char*)bnd + (size_t)b * SEQ;
    const int* p32 = (const int*)bnd + (size_t)b * SEQ;

    // pass 1: total count
    int total = 0;
    for (int base = 0; base < SEQ; base += 64) {
        const int s = base + lane;
        const int v = u8 ? (p8[s] != 0) : (p32[s] != 0);
        unsigned long long bal = __ballot(v);
        total += __popcll(bal);
    }
    if (lane == 0) {
        ntok[b] = total;
        ntok_out[b] = (float)total;  // output 1 (num_tokens), exact in fp32
    }

    // pass 2: destination for every position (stable partition)
    int cnt = 0;  // boundaries seen before this 64-chunk
    for (int base = 0; base < SEQ; base += 64) {
        const int s = base + lane;
        const int v = u8 ? (p8[s] != 0) : (p32[s] != 0);
        unsigned long long bal = __ballot(v);
        const int pre = __popcll(bal & ((1ull << lane) - 1ull));
        // boundary: rank among boundaries; non-boundary: total + rank among non-boundaries
        const int nb_before = cnt + pre;           // boundaries strictly before s
        const int dest = v ? nb_before : (total + s - nb_before);
        if (dest < MC) srcmap[(size_t)b * MC + dest] = s;
        cnt += __popcll(bal);
    }
}

// One block per output row: 256 threads x float4 = 4 KB row copy.
__global__ void gather_kernel(const float* __restrict__ x, const int* __restrict__ srcmap,
                              float* __restrict__ out, int MC) {
    const int c = blockIdx.x;
    const int b = blockIdx.y;
    const int s = srcmap[(size_t)b * MC + c];
    const float4* __restrict__ in = (const float4*)(x + ((size_t)b * SEQ + s) * DIM);
    float4* __restrict__ o = (float4*)(out + ((size_t)b * MC + c) * DIM);
    o[threadIdx.x] = in[threadIdx.x];
}

extern "C" void kernel_launch(void* const* d_in, const int* in_sizes, int n_in,
                              void* d_out, int out_size, void* d_ws, size_t ws_size,
                              hipStream_t stream) {
    const float* x = (const float*)d_in[0];
    const void* bnd = d_in[1];
    float* out = (float*)d_out;

    // out layout: [B, MC, D] hidden states, then [B] num_tokens (as float32)
    const int MC = (out_size - BATCH) / (BATCH * DIM);

    int* flag = (int*)d_ws;
    int* ntok = flag + 8;
    int* srcmap = ntok + BATCH + 8;

    hipMemsetAsync(flag, 0, sizeof(int), stream);
    detect_u8_kernel<<<64, 256, 0, stream>>>((const unsigned char*)bnd, BATCH * SEQ, flag);
    scan_kernel<<<BATCH, 64, 0, stream>>>(bnd, flag, ntok, srcmap,
                                          out + (size_t)BATCH * MC * DIM, MC);
    gather_kernel<<<dim3(MC, BATCH), 256, 0, stream>>>(x, srcmap, out, MC);
}

// Round 2
// 49.535 us; speedup vs baseline: 2.4981x; 2.4981x over previous
//
#include <hip/hip_runtime.h>

#define BATCH 8
#define SEQ 8192
#define DIM 1024

// One 1024-thread block per batch. Each thread handles 8 consecutive
// positions. Single pass:
//   1. per-block detection of u8-vs-int32 boundary storage (bytes at
//      offset%4!=0 are all zero iff int32 0/1 little-endian),
//   2. wave-level shfl_up inclusive scan of per-thread boundary counts,
//   3. cross-wave exclusive scan via LDS,
//   4. stable-partition dest for each position; record source row while
//      dest < MC; write num_tokens (fp32) for output 1.
__global__ __launch_bounds__(1024) void scan_kernel(
    const void* __restrict__ bnd, int* __restrict__ srcmap,
    float* __restrict__ ntok_out, int MC) {
    const int b = blockIdx.x;
    const int t = threadIdx.x;          // 0..1023
    const int lane = t & 63;
    const int wid = t >> 6;             // 0..15

    __shared__ int sh_u8;
    __shared__ int wave_tot[16];
    __shared__ int wave_pref[17];

    if (t == 0) sh_u8 = 0;
    __syncthreads();

    // Load 8 bytes (covers 8 positions if u8, 2 positions if i32 — but we
    // only use it for detection + the u8 path).
    const unsigned char* p8 = (const unsigned char*)bnd + (size_t)b * SEQ;
    const unsigned long long raw = ((const unsigned long long*)p8)[t];
    // bytes at local j=1,2,3,5,6,7 have global offset %4 != 0
    if (raw & 0xFFFFFF00FFFFFF00ull) sh_u8 = 1;  // benign same-value race
    __syncthreads();
    const bool u8 = (sh_u8 != 0);

    // bits[j] = boundary at position t*8+j
    unsigned int bits = 0;
    if (u8) {
#pragma unroll
        for (int j = 0; j < 8; ++j)
            if ((raw >> (8 * j)) & 0xFFull) bits |= 1u << j;
    } else {
        const int4* p32 = (const int4*)((const int*)bnd + (size_t)b * SEQ);
        const int4 q0 = p32[t * 2];
        const int4 q1 = p32[t * 2 + 1];
        bits = (q0.x != 0) | ((q0.y != 0) << 1) | ((q0.z != 0) << 2) |
               ((q0.w != 0) << 3) | ((q1.x != 0) << 4) | ((q1.y != 0) << 5) |
               ((q1.z != 0) << 6) | ((q1.w != 0) << 7);
    }
    const int c = __popc(bits);

    // wave-level inclusive scan of c
    int scan = c;
#pragma unroll
    for (int off = 1; off < 64; off <<= 1) {
        const int n = __shfl_up(scan, off);
        if (lane >= off) scan += n;
    }
    const int excl = scan - c;
    if (lane == 63) wave_tot[wid] = scan;
    __syncthreads();
    if (t == 0) {
        int acc = 0;
#pragma unroll
        for (int i = 0; i < 16; ++i) { wave_pref[i] = acc; acc += wave_tot[i]; }
        wave_pref[16] = acc;
    }
    __syncthreads();

    const int total = wave_pref[16];
    int P = wave_pref[wid] + excl;      // boundaries strictly before t*8
    const int s0 = t * 8;
    int* __restrict__ sm = srcmap + (size_t)b * MC;
#pragma unroll
    for (int j = 0; j < 8; ++j) {
        const int s = s0 + j;
        const int v = (bits >> j) & 1;
        const int dest = v ? P : (total + s - P);
        if (dest < MC) sm[dest] = s;
        P += v;
    }
    if (t == 0) ntok_out[b] = (float)total;  // exact in fp32 (<= 8192)
}

// One block per output row: 256 threads x float4 = 4 KB row copy.
__global__ void gather_kernel(const float* __restrict__ x,
                              const int* __restrict__ srcmap,
                              float* __restrict__ out, int MC) {
    const int c = blockIdx.x;
    const int b = blockIdx.y;
    const int s = srcmap[(size_t)b * MC + c];
    const float4* __restrict__ in = (const float4*)(x + ((size_t)b * SEQ + s) * DIM);
    float4* __restrict__ o = (float4*)(out + ((size_t)b * MC + c) * DIM);
    o[threadIdx.x] = in[threadIdx.x];
}

extern "C" void kernel_launch(void* const* d_in, const int* in_sizes, int n_in,
                              void* d_out, int out_size, void* d_ws, size_t ws_size,
                              hipStream_t stream) {
    const float* x = (const float*)d_in[0];
    const void* bnd = d_in[1];
    float* out = (float*)d_out;

    // out layout: [B, MC, D] hidden states, then [B] num_tokens (as float32)
    const int MC = (out_size - BATCH) / (BATCH * DIM);

    int* srcmap = (int*)d_ws;

    scan_kernel<<<BATCH, 1024, 0, stream>>>(bnd, srcmap,
                                            out + (size_t)BATCH * MC * DIM, MC);
    gather_kernel<<<dim3(MC, BATCH), 256, 0, stream>>>(x, srcmap, out, MC);
}